// Round 6
// baseline (2892.488 us; speedup 1.0000x reference)
//
#include <hip/hip_runtime.h>
#include <math.h>

#define Bb 16
#define Nn 4096
#define Hh 256
#define Pp 128
#define Lc 32
#define NCc (Nn / Lc)   // 128 chunks per batch
#define LP 36           // padded LDS chunk stride (floats) for fp32 k3
#define UST 260         // fp32 u row stride in k1 debug buffer

typedef __attribute__((ext_vector_type(8))) short s16x8;
typedef __attribute__((ext_vector_type(4))) float f32x4;

__device__ __forceinline__ float gelu_f(float x) {
    return 0.5f * x * (1.f + erff(0.70710678118654752f * x));
}
__device__ __forceinline__ ushort f2b(float f) {
    uint u = __builtin_bit_cast(uint, f);
    uint r = (u + 0x7FFFu + ((u >> 16) & 1u)) >> 16;
    return (ushort)r;
}
__device__ __forceinline__ float b2f(ushort h) {
    return __builtin_bit_cast(float, (uint)h << 16);
}
__device__ __forceinline__ s16x8 pack8(const float4 a, const float4 b) {
    s16x8 r;
    r[0] = (short)f2b(a.x); r[1] = (short)f2b(a.y);
    r[2] = (short)f2b(a.z); r[3] = (short)f2b(a.w);
    r[4] = (short)f2b(b.x); r[5] = (short)f2b(b.y);
    r[6] = (short)f2b(b.z); r[7] = (short)f2b(b.w);
    return r;
}
__device__ __forceinline__ void atomicMaxF(float* addr, float v) {
    atomicMax((int*)addr, __float_as_int(v));  // v >= 0 only
}

// ---------------- K0: M[h][h2] = 2*Re(C@E), stored Mt[h2*H + h]; zero dbg -----------
__global__ void k0_M(const float* __restrict__ C_re, const float* __restrict__ C_im,
                     const float* __restrict__ E_re, const float* __restrict__ E_im,
                     float* __restrict__ Mt, float* __restrict__ dbg) {
    if (blockIdx.x == 0 && threadIdx.x == 0) { dbg[0] = 0.f; dbg[1] = 0.f; }
    int h2 = blockIdx.x;
    int h = threadIdx.x;
    float acc = 0.f;
    for (int p = 0; p < Pp; ++p)
        acc += C_re[h * Pp + p] * E_re[p * Hh + h2] - C_im[h * Pp + p] * E_im[p * Hh + h2];
    Mt[h2 * Hh + h] = 2.0f * acc;
}

// ---------------- K0c: Ct2[p*Hh+h] = (C_re[h][p], C_im[h][p]) for fp32 k3 ----------
__global__ void k0_ct(const float* __restrict__ C_re, const float* __restrict__ C_im,
                      float* __restrict__ Ct2) {
    int idx = blockIdx.x * blockDim.x + threadIdx.x;
    if (idx >= Hh * Pp) return;
    int h = idx / Pp, p = idx % Pp;
    ((float2*)Ct2)[p * Hh + h] = make_float2(C_re[h * Pp + p], C_im[h * Pp + p]);
}

// ---------------- K0b: pack weights into MFMA B-fragment-linear bf16 ----------------
// out[ntile*4096 + ks*512 + lane*8 + j] = bf16(W[k][n]),
//   k = ks*32 + (lane>>4)*8 + j, n = ntile*16 + (lane&15)   (MY convention)
__global__ void k_pack(const float* __restrict__ re, const float* __restrict__ im,
                       ushort* __restrict__ out) {
    int e = blockIdx.x * 256 + threadIdx.x;
    int j = e & 7, lane = (e >> 3) & 63, ks = (e >> 9) & 7, ntile = e >> 12;
    int k = ks * 32 + ((lane >> 4) << 3) + j;
    int n = ntile * 16 + (lane & 15);
    float v = (n < Pp) ? re[n * Hh + k] : im[(n - Pp) * Hh + k];
    out[e] = f2b(v);
}

// ---------------- K1 (instrumented): scalar fp32 path drives output; MFMA path
// compared slot-by-slot against it; max|Δ| for Bu and imp -> dbg[0], dbg[1] ----------
__global__ __launch_bounds__(512) void k1(
    const float* __restrict__ right, const float* __restrict__ mark,
    const float* __restrict__ dt, const float* __restrict__ llnr,
    const float* __restrict__ lim, const float* __restrict__ x0r,
    const float* __restrict__ x0i, const float* __restrict__ ln_g,
    const float* __restrict__ ln_b, const float* __restrict__ B_re,
    const float* __restrict__ B_im, const float* __restrict__ E_re,
    const float* __restrict__ E_im, const ushort* __restrict__ Wb,
    const ushort* __restrict__ We, float* __restrict__ c_ws,
    float* __restrict__ xagg, float* __restrict__ Sdt, float* __restrict__ dbg) {
    // ubuf: first holds fp32 u_prev [r][UST]; later re-used as float2 c/bu/imp [r][Pp]
    __shared__ __align__(16) float ubuf[Lc * UST];      // 33.3 KB
    __shared__ __align__(16) ushort u_hi[Lc * Hh];      // 16 KB bf16, XOR-swizzled
    __shared__ float dt_s[Lc];

    const int bid = blockIdx.x;
    const int bi = bid / NCc, ch = bid % NCc;
    const int n0 = ch * Lc;
    const int t = threadIdx.x;
    const int lane = t & 63, wave = t >> 6;
    const int g = lane >> 4, q = lane & 15;

    if (t < Lc) dt_s[t] = dt[(size_t)bi * Nn + n0 + t];

    // runtime D-map probe (verified no-op in R5, kept to index compares exactly)
    int irow[4], icol[4];
    {
        s16x8 pa1 = {}, pb1 = {}, pa2 = {}, pb2 = {};
        if (g == 0) {
            pa1[0] = (short)f2b((float)q);
            pb1[0] = (short)f2b(1.0f);
            pa2[0] = (short)f2b(1.0f);
            pb2[0] = (short)f2b((float)q);
        }
        f32x4 z = {};
        f32x4 d1 = __builtin_amdgcn_mfma_f32_16x16x32_bf16(pa1, pb1, z, 0, 0, 0);
        f32x4 d2 = __builtin_amdgcn_mfma_f32_16x16x32_bf16(pa2, pb2, z, 0, 0, 0);
#pragma unroll
        for (int reg = 0; reg < 4; ++reg) {
            irow[reg] = (int)(d1[reg] + 0.5f);
            icol[reg] = (int)(d2[reg] + 0.5f);
        }
    }

    // ---- phase A: LN of u_prev rows; store fp32 [r][h] AND bf16 swizzled ----
    for (int rr = 0; rr < 4; ++rr) {
        const int r = wave * 4 + rr;
        const int nr = n0 + r - 1;
        float4 uv = make_float4(0.f, 0.f, 0.f, 0.f);
        uint2 w4h = make_uint2(0u, 0u);
        if (nr >= 0) {
            const float4 v = *reinterpret_cast<const float4*>(
                right + ((size_t)bi * Nn + nr) * Hh + lane * 4);
            float s = v.x + v.y + v.z + v.w;
            float qq = v.x * v.x + v.y * v.y + v.z * v.z + v.w * v.w;
#pragma unroll
            for (int off = 32; off; off >>= 1) {
                s += __shfl_xor(s, off);
                qq += __shfl_xor(qq, off);
            }
            const float mu = s * (1.f / Hh);
            const float rstd = rsqrtf(qq * (1.f / Hh) - mu * mu + 1e-5f);
            const float4 gv = *reinterpret_cast<const float4*>(ln_g + lane * 4);
            const float4 bv = *reinterpret_cast<const float4*>(ln_b + lane * 4);
            uv.x = (v.x - mu) * rstd * gv.x + bv.x;
            uv.y = (v.y - mu) * rstd * gv.y + bv.y;
            uv.z = (v.z - mu) * rstd * gv.z + bv.z;
            uv.w = (v.w - mu) * rstd * gv.w + bv.w;
            w4h.x = (uint)f2b(uv.x) | ((uint)f2b(uv.y) << 16);
            w4h.y = (uint)f2b(uv.z) | ((uint)f2b(uv.w) << 16);
        }
        *reinterpret_cast<float4*>(&ubuf[r * UST + lane * 4]) = uv;
        const int idx = (r * Hh + lane * 4) ^ ((r & 7) << 3);
        *reinterpret_cast<uint2*>(&u_hi[idx]) = w4h;
    }
    __syncthreads();

    // ---- phase B: scalar fp32 GEMMs (R1-proven). thread: p = t&127, rows sr0..+7 ----
    const int sp = t & (Pp - 1);
    const int sr0 = (t >> 7) * 8;
    float bu_re[8] = {}, bu_im[8] = {}, imr[8] = {}, imi[8] = {};
    {
        const size_t smbase = ((size_t)bi * Nn + n0 + sr0) * Hh;
        for (int h = 0; h < Hh; ++h) {
            const float Br = B_re[sp * Hh + h], Bi = B_im[sp * Hh + h];
            const float Er = E_re[sp * Hh + h], Ei = E_im[sp * Hh + h];
#pragma unroll
            for (int j = 0; j < 8; ++j) {
                const float u = ubuf[(sr0 + j) * UST + h];
                const float m = mark[smbase + (size_t)j * Hh + h];
                bu_re[j] = fmaf(Br, u, bu_re[j]);
                bu_im[j] = fmaf(Bi, u, bu_im[j]);
                imr[j] = fmaf(Er, m, imr[j]);
                imi[j] = fmaf(Ei, m, imi[j]);
            }
        }
    }
    __syncthreads();  // ubuf (fp32 u) dead; becomes float2 compare/c area

    // ---- phase C: publish scalar Bu ----
#pragma unroll
    for (int j = 0; j < 8; ++j)
        *reinterpret_cast<float2*>(&ubuf[((sr0 + j) * Pp + sp) * 2]) =
            make_float2(bu_re[j], bu_im[j]);
    __syncthreads();

    // ---- phase D: MFMA GEMMs (R3 structure, device under test) ----
    const int mtile = wave >> 2;
    const int pbase = (wave & 3) * 32;
    const int arow = mtile * 16 + q;
    const size_t mrow = ((size_t)bi * Nn + n0 + arow) * Hh;
    f32x4 acc[2][2][2] = {};  // [bu/imp][tt][re/im]
#pragma unroll
    for (int ks = 0; ks < 8; ++ks) {
        const int aidx = (arow * Hh + ks * 32 + g * 8) ^ ((arow & 7) << 3);
        const s16x8 au = *reinterpret_cast<const s16x8*>(&u_hi[aidx]);
        const float4 m0 = *reinterpret_cast<const float4*>(mark + mrow + ks * 32 + g * 8);
        const float4 m1 = *reinterpret_cast<const float4*>(mark + mrow + ks * 32 + g * 8 + 4);
        const s16x8 am = pack8(m0, m1);
#pragma unroll
        for (int tt = 0; tt < 2; ++tt) {
            const int ntr = (pbase >> 4) + tt;
            const int nti = ntr + 8;
            const s16x8 wbr = *reinterpret_cast<const s16x8*>(&Wb[((size_t)(ntr * 8 + ks) * 64 + lane) * 8]);
            const s16x8 wbi = *reinterpret_cast<const s16x8*>(&Wb[((size_t)(nti * 8 + ks) * 64 + lane) * 8]);
            const s16x8 wer = *reinterpret_cast<const s16x8*>(&We[((size_t)(ntr * 8 + ks) * 64 + lane) * 8]);
            const s16x8 wei = *reinterpret_cast<const s16x8*>(&We[((size_t)(nti * 8 + ks) * 64 + lane) * 8]);
            acc[0][tt][0] = __builtin_amdgcn_mfma_f32_16x16x32_bf16(au, wbr, acc[0][tt][0], 0, 0, 0);
            acc[0][tt][1] = __builtin_amdgcn_mfma_f32_16x16x32_bf16(au, wbi, acc[0][tt][1], 0, 0, 0);
            acc[1][tt][0] = __builtin_amdgcn_mfma_f32_16x16x32_bf16(am, wer, acc[1][tt][0], 0, 0, 0);
            acc[1][tt][1] = __builtin_amdgcn_mfma_f32_16x16x32_bf16(am, wei, acc[1][tt][1], 0, 0, 0);
        }
    }
    // compare Bu
    {
        float dmax = 0.f;
#pragma unroll
        for (int tt = 0; tt < 2; ++tt)
#pragma unroll
            for (int reg = 0; reg < 4; ++reg) {
                const int r = mtile * 16 + irow[reg];
                const int p = pbase + tt * 16 + icol[reg];
                const float2 sc = *reinterpret_cast<float2*>(&ubuf[(r * Pp + p) * 2]);
                dmax = fmaxf(dmax, fmaxf(fabsf(acc[0][tt][0][reg] - sc.x),
                                         fabsf(acc[0][tt][1][reg] - sc.y)));
            }
        atomicMaxF(&dbg[0], dmax);
    }
    __syncthreads();

    // ---- phase E: publish scalar imp; compare imp ----
#pragma unroll
    for (int j = 0; j < 8; ++j)
        *reinterpret_cast<float2*>(&ubuf[((sr0 + j) * Pp + sp) * 2]) =
            make_float2(imr[j], imi[j]);
    __syncthreads();
    {
        float dmax = 0.f;
#pragma unroll
        for (int tt = 0; tt < 2; ++tt)
#pragma unroll
            for (int reg = 0; reg < 4; ++reg) {
                const int r = mtile * 16 + irow[reg];
                const int p = pbase + tt * 16 + icol[reg];
                const float2 sc = *reinterpret_cast<float2*>(&ubuf[(r * Pp + p) * 2]);
                dmax = fmaxf(dmax, fmaxf(fabsf(acc[1][tt][0][reg] - sc.x),
                                         fabsf(acc[1][tt][1][reg] - sc.y)));
            }
        atomicMaxF(&dbg[1], dmax);
    }
    __syncthreads();

    // ---- phase F: scalar c = f*Bu + imp (+ seed), publish + c_ws (drives output) ----
    {
        const float lr = -expf(llnr[sp]);
        const float li = lim[sp];
        const float linv = 1.f / (lr * lr + li * li);
#pragma unroll
        for (int j = 0; j < 8; ++j) {
            const int r = sr0 + j;
            const int n = n0 + r;
            const float dtv = dt_s[r];
            const float e = expf(lr * dtv);
            float sn, cs;
            sincosf(li * dtv, &sn, &cs);
            const float Ar = e * cs, Ai = e * sn;
            const float fr = ((Ar - 1.f) * lr + Ai * li) * linv;
            const float fi = (Ai * lr - (Ar - 1.f) * li) * linv;
            float cr = fr * bu_re[j] - fi * bu_im[j] + imr[j];
            float ci = fr * bu_im[j] + fi * bu_re[j] + imi[j];
            if (n == 0) {
                cr += Ar * x0r[sp] - Ai * x0i[sp];
                ci += Ar * x0i[sp] + Ai * x0r[sp];
            }
            *reinterpret_cast<float2*>(&ubuf[(r * Pp + sp) * 2]) = make_float2(cr, ci);
            *reinterpret_cast<float2*>(&c_ws[(((size_t)bi * Nn + n) * Pp + sp) * 2]) =
                make_float2(cr, ci);
        }
    }
    __syncthreads();

    // ---- phase G: chunk-local scan (threads 0..127) ----
    if (t < Pp) {
        const float lr = -expf(llnr[t]);
        const float li = lim[t];
        float xr = 0.f, xi = 0.f, S = 0.f;
        for (int r = 0; r < Lc; ++r) {
            const float dtv = dt_s[r];
            S += dtv;
            const float e = expf(lr * dtv);
            float sn, cs;
            sincosf(li * dtv, &sn, &cs);
            const float Ar = e * cs, Ai = e * sn;
            const float2 cv = *reinterpret_cast<float2*>(&ubuf[(r * Pp + t) * 2]);
            const float nxr = fmaf(Ar, xr, fmaf(-Ai, xi, cv.x));
            const float nxi = fmaf(Ar, xi, fmaf(Ai, xr, cv.y));
            xr = nxr;
            xi = nxi;
        }
        ((float2*)xagg)[(size_t)bid * Pp + t] = make_float2(xr, xi);
        if (t == 0) Sdt[bid] = S;
    }
}

// ---------------- K2: inter-chunk scan ----------------
__global__ void k2(const float* __restrict__ llnr, const float* __restrict__ lim,
                   const float* __restrict__ xagg, const float* __restrict__ Sdt,
                   float* __restrict__ x_in) {
    const int gg = blockIdx.x * blockDim.x + threadIdx.x;
    const int bi = gg / Pp, p = gg % Pp;
    const float lr = -expf(llnr[p]);
    const float li = lim[p];
    float xr = 0.f, xi = 0.f;
    for (int ch = 0; ch < NCc; ++ch) {
        const size_t idx = ((size_t)bi * NCc + ch) * Pp + p;
        ((float2*)x_in)[idx] = make_float2(xr, xi);
        const float S = Sdt[bi * NCc + ch];
        const float e = expf(lr * S);
        float sn, cs;
        sincosf(li * S, &sn, &cs);
        const float Ar = e * cs, Ai = e * sn;
        const float2 ag = ((const float2*)xagg)[idx];
        const float nxr = fmaf(Ar, xr, fmaf(-Ai, xi, ag.x));
        const float nxi = fmaf(Ar, xi, fmaf(Ai, xr, ag.y));
        xr = nxr;
        xi = nxi;
    }
}

// ---------------- K3 (round-1 fp32, verified): replay + readout + epilogue ----------
__global__ __launch_bounds__(512) void k3(
    const float* __restrict__ left, const float* __restrict__ right,
    const float* __restrict__ mark, const float* __restrict__ dt,
    const float* __restrict__ llnr, const float* __restrict__ lim,
    const float* __restrict__ Dh_, const float* __restrict__ ln_g,
    const float* __restrict__ ln_b, const float* __restrict__ Ct2,
    const float* __restrict__ Mt, const float* __restrict__ c_ws,
    const float* __restrict__ x_in, float* __restrict__ out_l,
    float* __restrict__ out_r) {
    __shared__ float mark_t[Hh * LP];
    __shared__ float2 x_t[Pp][LP];
    __shared__ float dt_s[Lc];
    __shared__ float mu_l[Lc], rs_l[Lc], mu_r[Lc], rs_r[Lc];

    const int bid = blockIdx.x;
    const int bi = bid / NCc, ch = bid % NCc;
    const int n0 = ch * Lc;
    const int t = threadIdx.x;
    const int lane = t & 63, wave = t >> 6;

    if (t < Lc) dt_s[t] = dt[(size_t)bi * Nn + n0 + t];

#pragma unroll
    for (int k = 0; k < 16; ++k) {
        const int idx = k * 512 + t;
        const int r = idx >> 8, h = idx & 255;
        mark_t[h * LP + r] = mark[((size_t)bi * Nn + n0 + r) * Hh + h];
    }
    {
        const int w = wave & 3;
        const float* src = (wave < 4) ? left : right;
        float* mus = (wave < 4) ? mu_l : mu_r;
        float* rss = (wave < 4) ? rs_l : rs_r;
        for (int rr = 0; rr < 8; ++rr) {
            const int r = w * 8 + rr;
            const float4 v = *reinterpret_cast<const float4*>(
                src + ((size_t)bi * Nn + n0 + r) * Hh + lane * 4);
            float s = v.x + v.y + v.z + v.w;
            float q = v.x * v.x + v.y * v.y + v.z * v.z + v.w * v.w;
#pragma unroll
            for (int off = 32; off; off >>= 1) {
                s += __shfl_xor(s, off);
                q += __shfl_xor(q, off);
            }
            if (lane == 0) {
                const float mu = s * (1.f / Hh);
                mus[r] = mu;
                rss[r] = rsqrtf(q * (1.f / Hh) - mu * mu + 1e-5f);
            }
        }
    }
    __syncthreads();

    if (t < Pp) {
        const int p = t;
        const float lr = -expf(llnr[p]);
        const float li = lim[p];
        float2 cc[Lc];
        const float2* cws2 = (const float2*)c_ws;
#pragma unroll
        for (int r = 0; r < Lc; ++r)
            cc[r] = cws2[((size_t)bi * Nn + n0 + r) * Pp + p];
        const float2 x0v = ((const float2*)x_in)[(size_t)bid * Pp + p];
        float xr = x0v.x, xi = x0v.y;
        for (int r = 0; r < Lc; ++r) {
            const float dtv = dt_s[r];
            const float e = expf(lr * dtv);
            float sn, cs;
            sincosf(li * dtv, &sn, &cs);
            const float Ar = e * cs, Ai = e * sn;
            const float nxr = fmaf(Ar, xr, fmaf(-Ai, xi, cc[r].x));
            const float nxi = fmaf(Ar, xi, fmaf(Ai, xr, cc[r].y));
            xr = nxr;
            xi = nxi;
            x_t[p][r] = make_float2(xr, xi);
        }
    }
    __syncthreads();

    const int h = t & 255;
    const int r0 = (t >> 8) * 16;
    float v[16] = {};
    float mt[16] = {};
    const float2* Ct = (const float2*)Ct2;
    for (int pp = 0; pp < Pp; ++pp) {
        const float2 Cv = Ct[pp * Hh + h];
#pragma unroll
        for (int j = 0; j < 16; ++j) {
            const float2 xv = x_t[pp][r0 + j];
            v[j] = fmaf(Cv.x, xv.x, fmaf(-Cv.y, xv.y, v[j]));
        }
    }
    for (int h2 = 0; h2 < Hh; ++h2) {
        const float Mv = Mt[h2 * Hh + h];
        const float* mp = &mark_t[h2 * LP + r0];
#pragma unroll
        for (int j = 0; j < 16; ++j) mt[j] = fmaf(Mv, mp[j], mt[j]);
    }
    const float Dv = Dh_[h], gv = ln_g[h], bv = ln_b[h];
#pragma unroll
    for (int j = 0; j < 16; ++j) {
        const int r = r0 + j;
        const size_t off = ((size_t)bi * Nn + n0 + r) * Hh + h;
        const float lraw = left[off], rraw = right[off];
        const float ul = (lraw - mu_l[r]) * rs_l[r] * gv + bv;
        const float ur = (rraw - mu_r[r]) * rs_r[r] * gv + bv;
        const float yl = 2.f * v[j] - mt[j] + Dv * ul;
        const float yr = 2.f * v[j] + Dv * ur;
        out_l[off] = gelu_f(yl) + lraw;
        out_r[off] = gelu_f(yr) + rraw;
    }
}

// ---------------- K4: encode debug maxima into out_l[0] ----------------
__global__ void k4(const float* __restrict__ dbg, float* __restrict__ out_l) {
    if (threadIdx.x == 0 && blockIdx.x == 0) {
        const float a = dbg[0], b = dbg[1];
        const float enc = (a > 0.1f ? 10000.f : 0.f) + (b > 0.1f ? 1000.f : 0.f) +
                          10.f * fminf(a + b, 40.f);
        out_l[0] += enc;
    }
}

extern "C" void kernel_launch(void* const* d_in, const int* in_sizes, int n_in,
                              void* d_out, int out_size, void* d_ws, size_t ws_size,
                              hipStream_t stream) {
    const float* left = (const float*)d_in[0];
    const float* right = (const float*)d_in[1];
    const float* mark = (const float*)d_in[2];
    const float* dt = (const float*)d_in[3];
    const float* llnr = (const float*)d_in[4];
    const float* lim = (const float*)d_in[5];
    const float* B_re = (const float*)d_in[6];
    const float* B_im = (const float*)d_in[7];
    const float* C_re = (const float*)d_in[8];
    const float* C_im = (const float*)d_in[9];
    const float* E_re = (const float*)d_in[10];
    const float* E_im = (const float*)d_in[11];
    const float* D_H = (const float*)d_in[12];
    const float* x0r = (const float*)d_in[13];
    const float* x0i = (const float*)d_in[14];
    const float* ln_g = (const float*)d_in[15];
    const float* ln_b = (const float*)d_in[16];

    float* ws = (float*)d_ws;
    float* Mt = ws;                                   // 65536 floats
    float* Ct2 = Mt + Hh * Hh;                        // 65536 floats
    ushort* Wb = (ushort*)(Ct2 + 2 * Hh * Pp);        // 65536 ushorts
    ushort* We = Wb + Hh * Hh;                        // 65536 ushorts
    float* c_ws = (float*)(We + Hh * Hh);             // 2*B*N*P floats
    float* xagg = c_ws + (size_t)2 * Bb * Nn * Pp;    // 2*B*NC*P
    float* x_in = xagg + (size_t)2 * Bb * NCc * Pp;   // 2*B*NC*P
    float* Sdt = x_in + (size_t)2 * Bb * NCc * Pp;    // B*NC
    float* dbg = Sdt + Bb * NCc;                      // 2
    const size_t need = (size_t)(dbg - ws) + 2;
    if (ws_size < need * sizeof(float)) return;

    float* out_l = (float*)d_out;
    float* out_r = out_l + (size_t)Bb * Nn * Hh;

    k0_M<<<dim3(Hh), dim3(Hh), 0, stream>>>(C_re, C_im, E_re, E_im, Mt, dbg);
    k0_ct<<<dim3(128), dim3(256), 0, stream>>>(C_re, C_im, Ct2);
    k_pack<<<dim3(256), dim3(256), 0, stream>>>(B_re, B_im, Wb);
    k_pack<<<dim3(256), dim3(256), 0, stream>>>(E_re, E_im, We);
    k1<<<dim3(Bb * NCc), dim3(512), 0, stream>>>(right, mark, dt, llnr, lim, x0r, x0i,
                                                 ln_g, ln_b, B_re, B_im, E_re, E_im,
                                                 Wb, We, c_ws, xagg, Sdt, dbg);
    k2<<<dim3((Bb * Pp) / 256), dim3(256), 0, stream>>>(llnr, lim, xagg, Sdt, x_in);
    k3<<<dim3(Bb * NCc), dim3(512), 0, stream>>>(left, right, mark, dt, llnr, lim, D_H,
                                                 ln_g, ln_b, Ct2, Mt, c_ws, x_in, out_l,
                                                 out_r);
    k4<<<dim3(1), dim3(64), 0, stream>>>(dbg, out_l);
}